// Round 4
// baseline (291.725 us; speedup 1.0000x reference)
//
#include <hip/hip_runtime.h>
#include <hip/hip_bf16.h>

// B=32, C=128, HW=4096.
//   E = [wB;wV]@x + bias ; expB/expV = exp(E) (bf16) ; ZB/ZV row sums
//   T[i,c] = sum_n expB[i,n]*x[c,n]
//   G[i,j] = ((T[i,:].wA[j,:])/ZB_i + bA[j]) / (4096*ZV_i)
//   out[j,n] = sum_i expV[i,n]*G[i,j]
// R4: occupancy push. R3 counters: k1 VGPR=160 -> 3 waves/SIMD -> 2 blocks/CU
//   = 8 waves/CU, latency-bound (MfmaUtil 12.5%, VALU 20%, HBM 18%). Fix by
//   SHRINKING per-wave state (not by decree as in R2): k1/k2 go to 512-thr /
//   8-wave blocks with per-wave tiles halved (eacc 16 regs, tacc 32 regs,
//   8-elem staging) so __launch_bounds__(512,4) (cap 128 VGPR) is safe ->
//   16 waves/CU. k2b folded into k3b staging (sums np partials inline).

#define B_  32
#define C_  128
#define HW_ 4096

typedef __attribute__((ext_vector_type(8))) __bf16 bf16x8;
typedef __attribute__((ext_vector_type(4))) float f32x4;

__device__ __forceinline__ unsigned int bf_rne(float f) {   // bf16 bits (RNE)
    unsigned int u = __float_as_uint(f);
    return (u + 0x7fffu + ((u >> 16) & 1u)) >> 16;
}
__device__ __forceinline__ float bf_hi(float f) {           // RNE-to-bf16, as fp32
    unsigned int u = __float_as_uint(f);
    return __uint_as_float((u + 0x7fffu + ((u >> 16) & 1u)) & 0xffff0000u);
}

// ---------------------------------------------------------------------------
// k0: split Wcat=[wB;wV] (256x128 fp32) into bf16 hi/lo arrays. grid 32x256.
__global__ __launch_bounds__(256) void k0_prep(
    const float* __restrict__ wB, const float* __restrict__ wV,
    unsigned short* __restrict__ Wh, unsigned short* __restrict__ Wl)
{
    int g = blockIdx.x * 256 + threadIdx.x;      // 0..8191 float4s
    int row = g >> 5, c4 = (g & 31) << 2;
    const float* src = (row < 128) ? &wB[row * 128] : &wV[(row - 128) * 128];
    float4 v = *(const float4*)&src[c4];
    float vv[4] = {v.x, v.y, v.z, v.w};
    unsigned int h[4], l[4];
#pragma unroll
    for (int e = 0; e < 4; ++e) {
        float hf = bf_hi(vv[e]);
        h[e] = __float_as_uint(hf) >> 16;
        l[e] = bf_rne(vv[e] - hf);
    }
    *(uint2*)&Wh[row * 128 + c4] = make_uint2(h[0] | (h[1] << 16), h[2] | (h[3] << 16));
    *(uint2*)&Wl[row * 128 + c4] = make_uint2(l[0] | (l[1] << 16), l[2] | (l[3] << 16));
}

// ---------------------------------------------------------------------------
// k1_fused: E-GEMM + exp + Z + expB/expVT copy-out. grid (16, 32), 512 thr =
// 8 waves, cap 128 VGPR. Per wave: 32 E-rows (mt=2), 32 n.
__global__ __launch_bounds__(512, 4) void k1_fused(
    const float* __restrict__ x,
    const unsigned short* __restrict__ Wh, const unsigned short* __restrict__ Wl,
    const float* __restrict__ bB, const float* __restrict__ bV,
    unsigned short* __restrict__ expB, unsigned short* __restrict__ expVT,
    float* __restrict__ Zcat)
{
    __shared__ unsigned short XT_h[32 * 136];   // [n][c] pitch 136 (E B-operand, hi)
    __shared__ unsigned short XT_l[32 * 136];
    __shared__ unsigned short EBs[128 * 40];    // expB [i][n] pitch 40
    __shared__ unsigned short EVs[32 * 136];    // expV [n][i] pitch 136
    __shared__ float bias_s[256];

    const int t = threadIdx.x;
    const int lane = t & 63, w = t >> 6;        // w = 0..7
    const int col16 = lane & 15, quad = lane >> 4;
    const int b = blockIdx.y;
    const int n0 = blockIdx.x * 256;
    const float* xb = x + (size_t)b * C_ * HW_;

    const int sn = t & 31;        // staging: this thread's n within subtile
    const int cq0 = t >> 5;       // staging: c-block (0..15), owns 8 c values

    const int rowbase = w * 32;               // E rows for this wave (0..255)
    const int lbase = (w & 3) * 32;           // row base within 128-row projection
    const int boff = (w < 4) ? 0 : 128;

    if (t < 256) bias_s[t] = (t < 128) ? bB[t] : bV[t - 128];

    float zacc[2][4];
#pragma unroll
    for (int i = 0; i < 2; ++i)
#pragma unroll
        for (int j = 0; j < 4; ++j) zacc[i][j] = 0.f;

    // prefetch subtile 0: thread owns x[c = cq0*8 + cc][n0 + sn]
    float xr[8];
#pragma unroll
    for (int cc = 0; cc < 8; ++cc)
        xr[cc] = xb[(size_t)(cq0 * 8 + cc) * HW_ + n0 + sn];

    for (int st = 0; st < 8; ++st) {
        // convert this subtile's x to bf16 hi/lo
        unsigned int hbits[8], lbits[8];
#pragma unroll
        for (int e = 0; e < 8; ++e) {
            float hf = bf_hi(xr[e]);
            hbits[e] = __float_as_uint(hf) >> 16;
            lbits[e] = bf_rne(xr[e] - hf);
        }
        __syncthreads();   // B1: previous subtile's XT reads / EB,EV writes done
        {
            int cb = cq0 * 8;
            *(uint4*)&XT_h[sn * 136 + cb] = make_uint4(
                hbits[0] | (hbits[1] << 16), hbits[2] | (hbits[3] << 16),
                hbits[4] | (hbits[5] << 16), hbits[6] | (hbits[7] << 16));
            *(uint4*)&XT_l[sn * 136 + cb] = make_uint4(
                lbits[0] | (lbits[1] << 16), lbits[2] | (lbits[3] << 16),
                lbits[4] | (lbits[5] << 16), lbits[6] | (lbits[7] << 16));
        }
        __syncthreads();   // B2: XT visible
        // prefetch next subtile (overlaps E compute)
        if (st < 7) {
            int ns2 = n0 + (st + 1) * 32;
#pragma unroll
            for (int cc = 0; cc < 8; ++cc)
                xr[cc] = xb[(size_t)(cq0 * 8 + cc) * HW_ + ns2 + sn];
        }

        // --- E-GEMM: wave computes rows rowbase..+31 x 32 n, K=128 (c), 3 terms
        f32x4 eacc[2][2];
#pragma unroll
        for (int i = 0; i < 2; ++i)
#pragma unroll
            for (int j = 0; j < 2; ++j) eacc[i][j] = (f32x4){0.f,0.f,0.f,0.f};
#pragma unroll
        for (int ks = 0; ks < 4; ++ks) {
            int kc = ks * 32 + quad * 8;
            bf16x8 xh0 = *(const bf16x8*)&XT_h[col16 * 136 + kc];
            bf16x8 xl0 = *(const bf16x8*)&XT_l[col16 * 136 + kc];
            bf16x8 xh1 = *(const bf16x8*)&XT_h[(16 + col16) * 136 + kc];
            bf16x8 xl1 = *(const bf16x8*)&XT_l[(16 + col16) * 136 + kc];
#pragma unroll
            for (int mt = 0; mt < 2; ++mt) {
                int row = rowbase + mt * 16 + col16;
                bf16x8 wh = *(const bf16x8*)&Wh[row * 128 + kc];
                bf16x8 wl = *(const bf16x8*)&Wl[row * 128 + kc];
                eacc[mt][0] = __builtin_amdgcn_mfma_f32_16x16x32_bf16(wh, xh0, eacc[mt][0], 0, 0, 0);
                eacc[mt][0] = __builtin_amdgcn_mfma_f32_16x16x32_bf16(wh, xl0, eacc[mt][0], 0, 0, 0);
                eacc[mt][0] = __builtin_amdgcn_mfma_f32_16x16x32_bf16(wl, xh0, eacc[mt][0], 0, 0, 0);
                eacc[mt][1] = __builtin_amdgcn_mfma_f32_16x16x32_bf16(wh, xh1, eacc[mt][1], 0, 0, 0);
                eacc[mt][1] = __builtin_amdgcn_mfma_f32_16x16x32_bf16(wh, xl1, eacc[mt][1], 0, 0, 0);
                eacc[mt][1] = __builtin_amdgcn_mfma_f32_16x16x32_bf16(wl, xh1, eacc[mt][1], 0, 0, 0);
            }
        }

        // --- epilogue: exp, Z accumulate, expB->EBs [i][n] / expV->EVs [n][i]
#pragma unroll
        for (int mt = 0; mt < 2; ++mt)
#pragma unroll
            for (int r = 0; r < 4; ++r) {
                int lrow = lbase + mt * 16 + quad * 4 + r;   // 0..127 within proj
                float bb = bias_s[boff + lrow];
                float e0 = __expf(eacc[mt][0][r] + bb);
                float e1 = __expf(eacc[mt][1][r] + bb);
                zacc[mt][r] += e0 + e1;
                if (w < 4) {
                    EBs[lrow * 40 + col16]      = (unsigned short)bf_rne(e0);
                    EBs[lrow * 40 + 16 + col16] = (unsigned short)bf_rne(e1);
                } else {
                    EVs[col16 * 136 + lrow]        = (unsigned short)bf_rne(e0);
                    EVs[(16 + col16) * 136 + lrow] = (unsigned short)bf_rne(e1);
                }
            }
        // --- wave-local copy-out (reads only data this wave wrote; per-wave
        //     in-order LDS => no barrier needed; B1 next iter protects reuse)
        if (w < 4) {
            // expB [b][i][n], this wave's rows w*32..+32, 32 n: 128 uint4
#pragma unroll
            for (int rep = 0; rep < 2; ++rep) {
                int idx = rep * 64 + lane;
                int il = w * 32 + (idx >> 2), nc = idx & 3;
                *(uint4*)&expB[((size_t)b * 128 + il) * HW_ + n0 + st * 32 + nc * 8] =
                    *(const uint4*)&EBs[il * 40 + nc * 8];
            }
        } else {
            // expVT [b][n][i], this wave's i-slice lv..lv+32, 32 n: 128 uint4
            int lv = (w - 4) * 32;
#pragma unroll
            for (int rep = 0; rep < 2; ++rep) {
                int idx = rep * 64 + lane;
                int nl = idx >> 2, i4 = idx & 3;
                *(uint4*)&expVT[((size_t)b * HW_ + n0 + st * 32 + nl) * 128 + lv + i4 * 8] =
                    *(const uint4*)&EVs[nl * 136 + lv + i4 * 8];
            }
        }
    }

    // Z atomics (one per row, reduced across col16 lanes first)
#pragma unroll
    for (int mt = 0; mt < 2; ++mt)
#pragma unroll
        for (int r = 0; r < 4; ++r) {
            float rs = zacc[mt][r];
            rs += __shfl_xor(rs, 1, 16);
            rs += __shfl_xor(rs, 2, 16);
            rs += __shfl_xor(rs, 4, 16);
            rs += __shfl_xor(rs, 8, 16);
            if (col16 == 0)
                atomicAdd(&Zcat[b * 256 + boff + lbase + mt * 16 + quad * 4 + r], rs);
        }
}

// ---------------------------------------------------------------------------
// k2_T: T_part[p][b][i][c] = sum_{n in chunk p} expB[i,n]*x[c,n].
// grid (np, 32), 512 thr = 8 waves (cap 128 VGPR), wave tile 64i x 32c.
__global__ __launch_bounds__(512, 4) void k2_T(
    const float* __restrict__ x, const unsigned short* __restrict__ expB,
    float* __restrict__ T_part, int np)
{
    __shared__ unsigned short XN_h[128 * 40];   // [c][n] pitch 40
    __shared__ unsigned short XN_l[128 * 40];

    const int t = threadIdx.x;
    const int lane = t & 63, w = t >> 6;        // 0..7
    const int col16 = lane & 15, quad = lane >> 4;
    const int b = blockIdx.y, p = blockIdx.x;
    const int nchunk = HW_ / np;
    const int n0 = p * nchunk;
    const int nsub = nchunk / 32;
    const float* xb = x + (size_t)b * C_ * HW_;
    const unsigned short* eb = expB + (size_t)b * C_ * HW_;

    const int mh = (w >> 2) * 64;             // i-half
    const int nh = (w & 3) * 32;              // c-quarter
    const int sc = t >> 2, sq = (t & 3) * 8;  // staging: c row, n offset (8 n)

    f32x4 tacc[4][2];
#pragma unroll
    for (int i = 0; i < 4; ++i)
#pragma unroll
        for (int j = 0; j < 2; ++j) tacc[i][j] = (f32x4){0.f,0.f,0.f,0.f};

    // prefetch subtile 0: 8 consecutive n for row sc
    float xr[8];
#pragma unroll
    for (int q = 0; q < 2; ++q)
        *(float4*)&xr[q * 4] = *(const float4*)&xb[(size_t)sc * HW_ + n0 + sq + q * 4];

    for (int st = 0; st < nsub; ++st) {
        unsigned int hbits[8], lbits[8];
#pragma unroll
        for (int e = 0; e < 8; ++e) {
            float hf = bf_hi(xr[e]);
            hbits[e] = __float_as_uint(hf) >> 16;
            lbits[e] = bf_rne(xr[e] - hf);
        }
        // A frags for this subtile (global, L2/L3-resident)
        bf16x8 a[4];
#pragma unroll
        for (int mt = 0; mt < 4; ++mt)
            a[mt] = *(const bf16x8*)&eb[(size_t)(mh + mt * 16 + col16) * HW_ + n0 + st * 32 + quad * 8];

        __syncthreads();   // B1: previous subtile's XN reads done
        *(uint4*)&XN_h[sc * 40 + sq] = make_uint4(
            hbits[0] | (hbits[1] << 16), hbits[2] | (hbits[3] << 16),
            hbits[4] | (hbits[5] << 16), hbits[6] | (hbits[7] << 16));
        *(uint4*)&XN_l[sc * 40 + sq] = make_uint4(
            lbits[0] | (lbits[1] << 16), lbits[2] | (lbits[3] << 16),
            lbits[4] | (lbits[5] << 16), lbits[6] | (lbits[7] << 16));
        __syncthreads();   // B2: XN visible
        if (st < nsub - 1) {
            int ns2 = n0 + (st + 1) * 32;
#pragma unroll
            for (int q = 0; q < 2; ++q)
                *(float4*)&xr[q * 4] = *(const float4*)&xb[(size_t)sc * HW_ + ns2 + sq + q * 4];
        }

        // --- T-GEMM: K=32 (this subtile), wave tile 64 i x 32 c
#pragma unroll
        for (int ct = 0; ct < 2; ++ct) {
            int c = nh + ct * 16 + col16;
            bf16x8 bh = *(const bf16x8*)&XN_h[c * 40 + quad * 8];
            bf16x8 bl = *(const bf16x8*)&XN_l[c * 40 + quad * 8];
#pragma unroll
            for (int mt = 0; mt < 4; ++mt) {
                tacc[mt][ct] = __builtin_amdgcn_mfma_f32_16x16x32_bf16(a[mt], bh, tacc[mt][ct], 0, 0, 0);
                tacc[mt][ct] = __builtin_amdgcn_mfma_f32_16x16x32_bf16(a[mt], bl, tacc[mt][ct], 0, 0, 0);
            }
        }
    }

    // store partials (no atomics)
    float* Tp = T_part + ((size_t)p * B_ + b) * 128 * 128;
#pragma unroll
    for (int mt = 0; mt < 4; ++mt)
#pragma unroll
        for (int ct = 0; ct < 2; ++ct)
#pragma unroll
            for (int r = 0; r < 4; ++r)
                Tp[(mh + mt * 16 + quad * 4 + r) * 128 + nh + ct * 16 + col16] = tacc[mt][ct][r];
}

// ---------------------------------------------------------------------------
// k3b: G transposed + 2-way bf16 split; sums T_part inline during staging.
// grid (8, 32), block 256, fp32 VALU. Tiles 64 j x 32 i.
__global__ __launch_bounds__(256) void k3b_G(
    const float* __restrict__ T_part, const float* __restrict__ wA,
    const float* __restrict__ bA, const float* __restrict__ Zcat,
    unsigned short* __restrict__ Gth, unsigned short* __restrict__ Gtm, int np)
{
    const int t = threadIdx.x;
    const int tx = t & 15, ty = t >> 4;
    const int b = blockIdx.y;
    const int jb = (blockIdx.x >> 2) * 64;
    const int ib = (blockIdx.x & 3) * 32;

    __shared__ float Ts[32][36];
    __shared__ float Wa[64][36];

    float acc[4][2];
#pragma unroll
    for (int i = 0; i < 4; ++i)
#pragma unroll
        for (int j = 0; j < 2; ++j) acc[i][j] = 0.f;

    for (int c0 = 0; c0 < 128; c0 += 32) {
        __syncthreads();
        {
            int r = t >> 3, kq = (t & 7) << 2;
            float4 s = make_float4(0.f, 0.f, 0.f, 0.f);
            for (int p = 0; p < np; ++p) {
                float4 v = *(const float4*)&T_part[(((size_t)p * B_ + b) * 128 + ib + r) * 128 + c0 + kq];
                s.x += v.x; s.y += v.y; s.z += v.z; s.w += v.w;
            }
            *(float4*)&Ts[r][kq] = s;
        }
#pragma unroll
        for (int it = 0; it < 2; ++it) {
            int idx = it * 256 + t;
            int r = idx >> 3, kq = (idx & 7) << 2;
            *(float4*)&Wa[r][kq] = *(const float4*)&wA[(jb + r) * 128 + c0 + kq];
        }
        __syncthreads();
#pragma unroll
        for (int k = 0; k < 32; k += 4) {
            float4 wv[4], tv[2];
#pragma unroll
            for (int jj = 0; jj < 4; ++jj) wv[jj] = *(const float4*)&Wa[jj * 16 + ty][k];
#pragma unroll
            for (int ii = 0; ii < 2; ++ii) tv[ii] = *(const float4*)&Ts[ii * 16 + tx][k];
#pragma unroll
            for (int jj = 0; jj < 4; ++jj)
#pragma unroll
                for (int ii = 0; ii < 2; ++ii) {
                    acc[jj][ii] = fmaf(wv[jj].x, tv[ii].x, acc[jj][ii]);
                    acc[jj][ii] = fmaf(wv[jj].y, tv[ii].y, acc[jj][ii]);
                    acc[jj][ii] = fmaf(wv[jj].z, tv[ii].z, acc[jj][ii]);
                    acc[jj][ii] = fmaf(wv[jj].w, tv[ii].w, acc[jj][ii]);
                }
        }
    }
    const float* ZB = Zcat + b * 256;
    const float* ZV = ZB + 128;
#pragma unroll
    for (int jj = 0; jj < 4; ++jj) {
        int j = jb + jj * 16 + ty;
        float bj = bA[j];
#pragma unroll
        for (int ii = 0; ii < 2; ++ii) {
            int i = ib + ii * 16 + tx;
            float g = (acc[jj][ii] / ZB[i] + bj) / (4096.f * ZV[i]);
            float h = bf_hi(g);  float r1 = g - h;
            float m = bf_hi(r1);
            size_t o = ((size_t)b * 128 + j) * 128 + i;
            Gth[o] = (unsigned short)(__float_as_uint(h) >> 16);
            Gtm[o] = (unsigned short)(__float_as_uint(m) >> 16);
        }
    }
}

// ---------------------------------------------------------------------------
// k4: out[b,j,n] = sum_i expVT[n][i] * Gt(j,i)  (MFMA, 2-term G split).
__global__ __launch_bounds__(256, 4) void k4_out(
    const unsigned short* __restrict__ expVT,
    const unsigned short* __restrict__ Gth, const unsigned short* __restrict__ Gtm,
    float* __restrict__ out)
{
    __shared__ unsigned short Vs[128 * 136];   // [n][i] pitch 136

    const int t = threadIdx.x;
    const int lane = t & 63, w = t >> 6;
    const int col16 = lane & 15, quad = lane >> 4;
    const int b = blockIdx.y, nb = blockIdx.x * 128;

#pragma unroll
    for (int it = 0; it < 8; ++it) {
        int idx = it * 256 + t;
        int n = idx >> 4, o = idx & 15;
        int o2 = (o + 4 * (n & 3)) & 15;
        *(uint4*)&Vs[n * 136 + o2 * 8] =
            *(const uint4*)&expVT[((size_t)b * HW_ + nb + n) * 128 + o2 * 8];
    }
    __syncthreads();

    f32x4 acc[8][2];
#pragma unroll
    for (int i = 0; i < 8; ++i)
#pragma unroll
        for (int j = 0; j < 2; ++j) acc[i][j] = (f32x4){0.f,0.f,0.f,0.f};

    const unsigned short* gh = Gth + (size_t)b * 128 * 128;
    const unsigned short* gm = Gtm + (size_t)b * 128 * 128;

#pragma unroll
    for (int ks = 0; ks < 4; ++ks) {
        int ko = ks * 32 + quad * 8;
        bf16x8 vfr[2];
#pragma unroll
        for (int nt = 0; nt < 2; ++nt) {
            int n = w * 32 + nt * 16 + col16;
            vfr[nt] = *(const bf16x8*)&Vs[n * 136 + ko];
        }
#pragma unroll
        for (int mt = 0; mt < 8; ++mt) {
            int j = mt * 16 + col16;
            bf16x8 ah = *(const bf16x8*)&gh[j * 128 + ko];
            bf16x8 am = *(const bf16x8*)&gm[j * 128 + ko];
#pragma unroll
            for (int nt = 0; nt < 2; ++nt) {
                acc[mt][nt] = __builtin_amdgcn_mfma_f32_16x16x32_bf16(ah, vfr[nt], acc[mt][nt], 0, 0, 0);
                acc[mt][nt] = __builtin_amdgcn_mfma_f32_16x16x32_bf16(am, vfr[nt], acc[mt][nt], 0, 0, 0);
            }
        }
    }
    float* ob = out + (size_t)b * C_ * HW_;
#pragma unroll
    for (int mt = 0; mt < 8; ++mt)
#pragma unroll
        for (int nt = 0; nt < 2; ++nt)
#pragma unroll
            for (int r = 0; r < 4; ++r) {
                int j = mt * 16 + quad * 4 + r;
                int n = nb + w * 32 + nt * 16 + col16;
                ob[(size_t)j * HW_ + n] = acc[mt][nt][r];
            }
}

// ---------------------------------------------------------------------------
extern "C" void kernel_launch(void* const* d_in, const int* in_sizes, int n_in,
                              void* d_out, int out_size, void* d_ws, size_t ws_size,
                              hipStream_t stream)
{
    const float* x  = (const float*)d_in[0];
    const float* wA = (const float*)d_in[1];
    const float* bA = (const float*)d_in[2];
    const float* wB = (const float*)d_in[3];
    const float* bB = (const float*)d_in[4];
    const float* wV = (const float*)d_in[5];
    const float* bV = (const float*)d_in[6];
    float* out = (float*)d_out;

    // workspace (~98 MiB at np=16):
    //   Zcat 32K | Wh 64K | Wl 64K | expB 32M | expVT 32M | T_part np*2M | G 2M
    char* ws = (char*)d_ws;
    float*          Zcat  = (float*)ws;                       // 32768
    unsigned short* Wh    = (unsigned short*)(ws + 32768);    // 65536
    unsigned short* Wl    = (unsigned short*)(ws + 98304);    // 65536
    unsigned short* expB  = (unsigned short*)(ws + 163840);   // 33554432
    unsigned short* expVT = (unsigned short*)(ws + 33718272); // 33554432
    float*          T_part= (float*)(ws + 67272704);          // np*2097152

    int np = 16;
    while (np > 1 && 67272704ull + (size_t)np * 2097152 + 2097152 > ws_size) np >>= 1;

    unsigned short* Gth = (unsigned short*)(ws + 67272704 + (size_t)np * 2097152);
    unsigned short* Gtm = Gth + 128 * 128 * 32;

    hipMemsetAsync(Zcat, 0, 32768, stream);   // Zcat only

    k0_prep <<<dim3(32),     256, 0, stream>>>(wB, wV, Wh, Wl);
    k1_fused<<<dim3(16, 32), 512, 0, stream>>>(x, Wh, Wl, bB, bV, expB, expVT, Zcat);
    k2_T    <<<dim3(np, 32), 512, 0, stream>>>(x, expB, T_part, np);
    k3b_G   <<<dim3(8, 32),  256, 0, stream>>>(T_part, wA, bA, Zcat, Gth, Gtm, np);
    k4_out  <<<dim3(32, 32), 256, 0, stream>>>(expVT, Gth, Gtm, out);
}

// Round 5
// 252.974 us; speedup vs baseline: 1.1532x; 1.1532x over previous
//
#include <hip/hip_runtime.h>
#include <hip/hip_bf16.h>

// B=32, C=128, HW=4096.
//   E = [wB;wV]@x + bias ; expB/expV = exp(E) (bf16) ; ZB/ZV row sums
//   T[i,c] = sum_n expB[i,n]*x[c,n]
//   G[i,j] = ((T[i,:].wA[j,:])/ZB_i + bA[j]) / (4096*ZV_i)
//   out[j,n] = sum_i expV[i,n]*G[i,j]
// R5: fix the launch_bounds semantics bug. R2/R4 evidence: (512,4) yields
//   VGPR=64 => 2nd arg behaves as MIN BLOCKS/CU (4 blk x 8 waves = 32 waves/CU
//   => cap 64), forcing spills (FETCH 34->87MB). Use (512,2): cap 128 under
//   blocks-semantics (working set ~100-110 fits), no-op under waves-semantics.
//   Structure unchanged from R4: k1 = E-GEMM+exp+copyout (8-wave blocks,
//   per-wave 32 E-rows), k2 = T-GEMM partials (8-wave, 64x32 wave tile),
//   k3b sums partials inline, k4 = out-GEMM.

#define B_  32
#define C_  128
#define HW_ 4096

typedef __attribute__((ext_vector_type(8))) __bf16 bf16x8;
typedef __attribute__((ext_vector_type(4))) float f32x4;

__device__ __forceinline__ unsigned int bf_rne(float f) {   // bf16 bits (RNE)
    unsigned int u = __float_as_uint(f);
    return (u + 0x7fffu + ((u >> 16) & 1u)) >> 16;
}
__device__ __forceinline__ float bf_hi(float f) {           // RNE-to-bf16, as fp32
    unsigned int u = __float_as_uint(f);
    return __uint_as_float((u + 0x7fffu + ((u >> 16) & 1u)) & 0xffff0000u);
}

// ---------------------------------------------------------------------------
// k0: split Wcat=[wB;wV] (256x128 fp32) into bf16 hi/lo arrays. grid 32x256.
__global__ __launch_bounds__(256) void k0_prep(
    const float* __restrict__ wB, const float* __restrict__ wV,
    unsigned short* __restrict__ Wh, unsigned short* __restrict__ Wl)
{
    int g = blockIdx.x * 256 + threadIdx.x;      // 0..8191 float4s
    int row = g >> 5, c4 = (g & 31) << 2;
    const float* src = (row < 128) ? &wB[row * 128] : &wV[(row - 128) * 128];
    float4 v = *(const float4*)&src[c4];
    float vv[4] = {v.x, v.y, v.z, v.w};
    unsigned int h[4], l[4];
#pragma unroll
    for (int e = 0; e < 4; ++e) {
        float hf = bf_hi(vv[e]);
        h[e] = __float_as_uint(hf) >> 16;
        l[e] = bf_rne(vv[e] - hf);
    }
    *(uint2*)&Wh[row * 128 + c4] = make_uint2(h[0] | (h[1] << 16), h[2] | (h[3] << 16));
    *(uint2*)&Wl[row * 128 + c4] = make_uint2(l[0] | (l[1] << 16), l[2] | (l[3] << 16));
}

// ---------------------------------------------------------------------------
// k1_fused: E-GEMM + exp + Z + expB/expVT copy-out. grid (16, 32), 512 thr =
// 8 waves. (512,2): 2 blocks/CU => 16 waves/CU, VGPR cap 128 (no spill).
__global__ __launch_bounds__(512, 2) void k1_fused(
    const float* __restrict__ x,
    const unsigned short* __restrict__ Wh, const unsigned short* __restrict__ Wl,
    const float* __restrict__ bB, const float* __restrict__ bV,
    unsigned short* __restrict__ expB, unsigned short* __restrict__ expVT,
    float* __restrict__ Zcat)
{
    __shared__ unsigned short XT_h[32 * 136];   // [n][c] pitch 136 (E B-operand, hi)
    __shared__ unsigned short XT_l[32 * 136];
    __shared__ unsigned short EBs[128 * 40];    // expB [i][n] pitch 40
    __shared__ unsigned short EVs[32 * 136];    // expV [n][i] pitch 136
    __shared__ float bias_s[256];

    const int t = threadIdx.x;
    const int lane = t & 63, w = t >> 6;        // w = 0..7
    const int col16 = lane & 15, quad = lane >> 4;
    const int b = blockIdx.y;
    const int n0 = blockIdx.x * 256;
    const float* xb = x + (size_t)b * C_ * HW_;

    const int sn = t & 31;        // staging: this thread's n within subtile
    const int cq0 = t >> 5;       // staging: c-block (0..15), owns 8 c values

    const int rowbase = w * 32;               // E rows for this wave (0..255)
    const int lbase = (w & 3) * 32;           // row base within 128-row projection
    const int boff = (w < 4) ? 0 : 128;

    if (t < 256) bias_s[t] = (t < 128) ? bB[t] : bV[t - 128];

    float zacc[2][4];
#pragma unroll
    for (int i = 0; i < 2; ++i)
#pragma unroll
        for (int j = 0; j < 4; ++j) zacc[i][j] = 0.f;

    // prefetch subtile 0: thread owns x[c = cq0*8 + cc][n0 + sn]
    float xr[8];
#pragma unroll
    for (int cc = 0; cc < 8; ++cc)
        xr[cc] = xb[(size_t)(cq0 * 8 + cc) * HW_ + n0 + sn];

    for (int st = 0; st < 8; ++st) {
        // convert this subtile's x to bf16 hi/lo
        unsigned int hbits[8], lbits[8];
#pragma unroll
        for (int e = 0; e < 8; ++e) {
            float hf = bf_hi(xr[e]);
            hbits[e] = __float_as_uint(hf) >> 16;
            lbits[e] = bf_rne(xr[e] - hf);
        }
        __syncthreads();   // B1: previous subtile's XT reads / EB,EV writes done
        {
            int cb = cq0 * 8;
            *(uint4*)&XT_h[sn * 136 + cb] = make_uint4(
                hbits[0] | (hbits[1] << 16), hbits[2] | (hbits[3] << 16),
                hbits[4] | (hbits[5] << 16), hbits[6] | (hbits[7] << 16));
            *(uint4*)&XT_l[sn * 136 + cb] = make_uint4(
                lbits[0] | (lbits[1] << 16), lbits[2] | (lbits[3] << 16),
                lbits[4] | (lbits[5] << 16), lbits[6] | (lbits[7] << 16));
        }
        __syncthreads();   // B2: XT visible
        // prefetch next subtile (overlaps E compute)
        if (st < 7) {
            int ns2 = n0 + (st + 1) * 32;
#pragma unroll
            for (int cc = 0; cc < 8; ++cc)
                xr[cc] = xb[(size_t)(cq0 * 8 + cc) * HW_ + ns2 + sn];
        }

        // --- E-GEMM: wave computes rows rowbase..+31 x 32 n, K=128 (c), 3 terms
        f32x4 eacc[2][2];
#pragma unroll
        for (int i = 0; i < 2; ++i)
#pragma unroll
            for (int j = 0; j < 2; ++j) eacc[i][j] = (f32x4){0.f,0.f,0.f,0.f};
#pragma unroll
        for (int ks = 0; ks < 4; ++ks) {
            int kc = ks * 32 + quad * 8;
            bf16x8 xh0 = *(const bf16x8*)&XT_h[col16 * 136 + kc];
            bf16x8 xl0 = *(const bf16x8*)&XT_l[col16 * 136 + kc];
            bf16x8 xh1 = *(const bf16x8*)&XT_h[(16 + col16) * 136 + kc];
            bf16x8 xl1 = *(const bf16x8*)&XT_l[(16 + col16) * 136 + kc];
#pragma unroll
            for (int mt = 0; mt < 2; ++mt) {
                int row = rowbase + mt * 16 + col16;
                bf16x8 wh = *(const bf16x8*)&Wh[row * 128 + kc];
                bf16x8 wl = *(const bf16x8*)&Wl[row * 128 + kc];
                eacc[mt][0] = __builtin_amdgcn_mfma_f32_16x16x32_bf16(wh, xh0, eacc[mt][0], 0, 0, 0);
                eacc[mt][0] = __builtin_amdgcn_mfma_f32_16x16x32_bf16(wh, xl0, eacc[mt][0], 0, 0, 0);
                eacc[mt][0] = __builtin_amdgcn_mfma_f32_16x16x32_bf16(wl, xh0, eacc[mt][0], 0, 0, 0);
                eacc[mt][1] = __builtin_amdgcn_mfma_f32_16x16x32_bf16(wh, xh1, eacc[mt][1], 0, 0, 0);
                eacc[mt][1] = __builtin_amdgcn_mfma_f32_16x16x32_bf16(wh, xl1, eacc[mt][1], 0, 0, 0);
                eacc[mt][1] = __builtin_amdgcn_mfma_f32_16x16x32_bf16(wl, xh1, eacc[mt][1], 0, 0, 0);
            }
        }

        // --- epilogue: exp, Z accumulate, expB->EBs [i][n] / expV->EVs [n][i]
#pragma unroll
        for (int mt = 0; mt < 2; ++mt)
#pragma unroll
            for (int r = 0; r < 4; ++r) {
                int lrow = lbase + mt * 16 + quad * 4 + r;   // 0..127 within proj
                float bb = bias_s[boff + lrow];
                float e0 = __expf(eacc[mt][0][r] + bb);
                float e1 = __expf(eacc[mt][1][r] + bb);
                zacc[mt][r] += e0 + e1;
                if (w < 4) {
                    EBs[lrow * 40 + col16]      = (unsigned short)bf_rne(e0);
                    EBs[lrow * 40 + 16 + col16] = (unsigned short)bf_rne(e1);
                } else {
                    EVs[col16 * 136 + lrow]        = (unsigned short)bf_rne(e0);
                    EVs[(16 + col16) * 136 + lrow] = (unsigned short)bf_rne(e1);
                }
            }
        // --- wave-local copy-out (reads only data this wave wrote; per-wave
        //     in-order LDS => no barrier needed; B1 next iter protects reuse)
        if (w < 4) {
            // expB [b][i][n], this wave's rows w*32..+32, 32 n: 128 uint4
#pragma unroll
            for (int rep = 0; rep < 2; ++rep) {
                int idx = rep * 64 + lane;
                int il = w * 32 + (idx >> 2), nc = idx & 3;
                *(uint4*)&expB[((size_t)b * 128 + il) * HW_ + n0 + st * 32 + nc * 8] =
                    *(const uint4*)&EBs[il * 40 + nc * 8];
            }
        } else {
            // expVT [b][n][i], this wave's i-slice lv..lv+32, 32 n: 128 uint4
            int lv = (w - 4) * 32;
#pragma unroll
            for (int rep = 0; rep < 2; ++rep) {
                int idx = rep * 64 + lane;
                int nl = idx >> 2, i4 = idx & 3;
                *(uint4*)&expVT[((size_t)b * HW_ + n0 + st * 32 + nl) * 128 + lv + i4 * 8] =
                    *(const uint4*)&EVs[nl * 136 + lv + i4 * 8];
            }
        }
    }

    // Z atomics (one per row, reduced across col16 lanes first)
#pragma unroll
    for (int mt = 0; mt < 2; ++mt)
#pragma unroll
        for (int r = 0; r < 4; ++r) {
            float rs = zacc[mt][r];
            rs += __shfl_xor(rs, 1, 16);
            rs += __shfl_xor(rs, 2, 16);
            rs += __shfl_xor(rs, 4, 16);
            rs += __shfl_xor(rs, 8, 16);
            if (col16 == 0)
                atomicAdd(&Zcat[b * 256 + boff + lbase + mt * 16 + quad * 4 + r], rs);
        }
}

// ---------------------------------------------------------------------------
// k2_T: T_part[p][b][i][c] = sum_{n in chunk p} expB[i,n]*x[c,n].
// grid (np, 32), 512 thr = 8 waves, (512,2) => cap 128 VGPR. Wave tile 64i x 32c.
__global__ __launch_bounds__(512, 2) void k2_T(
    const float* __restrict__ x, const unsigned short* __restrict__ expB,
    float* __restrict__ T_part, int np)
{
    __shared__ unsigned short XN_h[128 * 40];   // [c][n] pitch 40
    __shared__ unsigned short XN_l[128 * 40];

    const int t = threadIdx.x;
    const int lane = t & 63, w = t >> 6;        // 0..7
    const int col16 = lane & 15, quad = lane >> 4;
    const int b = blockIdx.y, p = blockIdx.x;
    const int nchunk = HW_ / np;
    const int n0 = p * nchunk;
    const int nsub = nchunk / 32;
    const float* xb = x + (size_t)b * C_ * HW_;
    const unsigned short* eb = expB + (size_t)b * C_ * HW_;

    const int mh = (w >> 2) * 64;             // i-half
    const int nh = (w & 3) * 32;              // c-quarter
    const int sc = t >> 2, sq = (t & 3) * 8;  // staging: c row, n offset (8 n)

    f32x4 tacc[4][2];
#pragma unroll
    for (int i = 0; i < 4; ++i)
#pragma unroll
        for (int j = 0; j < 2; ++j) tacc[i][j] = (f32x4){0.f,0.f,0.f,0.f};

    // prefetch subtile 0: 8 consecutive n for row sc
    float xr[8];
#pragma unroll
    for (int q = 0; q < 2; ++q)
        *(float4*)&xr[q * 4] = *(const float4*)&xb[(size_t)sc * HW_ + n0 + sq + q * 4];

    for (int st = 0; st < nsub; ++st) {
        unsigned int hbits[8], lbits[8];
#pragma unroll
        for (int e = 0; e < 8; ++e) {
            float hf = bf_hi(xr[e]);
            hbits[e] = __float_as_uint(hf) >> 16;
            lbits[e] = bf_rne(xr[e] - hf);
        }
        // A frags for this subtile (global, L2/L3-resident)
        bf16x8 a[4];
#pragma unroll
        for (int mt = 0; mt < 4; ++mt)
            a[mt] = *(const bf16x8*)&eb[(size_t)(mh + mt * 16 + col16) * HW_ + n0 + st * 32 + quad * 8];

        __syncthreads();   // B1: previous subtile's XN reads done
        *(uint4*)&XN_h[sc * 40 + sq] = make_uint4(
            hbits[0] | (hbits[1] << 16), hbits[2] | (hbits[3] << 16),
            hbits[4] | (hbits[5] << 16), hbits[6] | (hbits[7] << 16));
        *(uint4*)&XN_l[sc * 40 + sq] = make_uint4(
            lbits[0] | (lbits[1] << 16), lbits[2] | (lbits[3] << 16),
            lbits[4] | (lbits[5] << 16), lbits[6] | (lbits[7] << 16));
        __syncthreads();   // B2: XN visible
        if (st < nsub - 1) {
            int ns2 = n0 + (st + 1) * 32;
#pragma unroll
            for (int q = 0; q < 2; ++q)
                *(float4*)&xr[q * 4] = *(const float4*)&xb[(size_t)sc * HW_ + ns2 + sq + q * 4];
        }

        // --- T-GEMM: K=32 (this subtile), wave tile 64 i x 32 c
#pragma unroll
        for (int ct = 0; ct < 2; ++ct) {
            int c = nh + ct * 16 + col16;
            bf16x8 bh = *(const bf16x8*)&XN_h[c * 40 + quad * 8];
            bf16x8 bl = *(const bf16x8*)&XN_l[c * 40 + quad * 8];
#pragma unroll
            for (int mt = 0; mt < 4; ++mt) {
                tacc[mt][ct] = __builtin_amdgcn_mfma_f32_16x16x32_bf16(a[mt], bh, tacc[mt][ct], 0, 0, 0);
                tacc[mt][ct] = __builtin_amdgcn_mfma_f32_16x16x32_bf16(a[mt], bl, tacc[mt][ct], 0, 0, 0);
            }
        }
    }

    // store partials (no atomics)
    float* Tp = T_part + ((size_t)p * B_ + b) * 128 * 128;
#pragma unroll
    for (int mt = 0; mt < 4; ++mt)
#pragma unroll
        for (int ct = 0; ct < 2; ++ct)
#pragma unroll
            for (int r = 0; r < 4; ++r)
                Tp[(mh + mt * 16 + quad * 4 + r) * 128 + nh + ct * 16 + col16] = tacc[mt][ct][r];
}

// ---------------------------------------------------------------------------
// k3b: G transposed + 2-way bf16 split; sums T_part inline during staging.
// grid (8, 32), block 256, fp32 VALU. Tiles 64 j x 32 i.
__global__ __launch_bounds__(256) void k3b_G(
    const float* __restrict__ T_part, const float* __restrict__ wA,
    const float* __restrict__ bA, const float* __restrict__ Zcat,
    unsigned short* __restrict__ Gth, unsigned short* __restrict__ Gtm, int np)
{
    const int t = threadIdx.x;
    const int tx = t & 15, ty = t >> 4;
    const int b = blockIdx.y;
    const int jb = (blockIdx.x >> 2) * 64;
    const int ib = (blockIdx.x & 3) * 32;

    __shared__ float Ts[32][36];
    __shared__ float Wa[64][36];

    float acc[4][2];
#pragma unroll
    for (int i = 0; i < 4; ++i)
#pragma unroll
        for (int j = 0; j < 2; ++j) acc[i][j] = 0.f;

    for (int c0 = 0; c0 < 128; c0 += 32) {
        __syncthreads();
        {
            int r = t >> 3, kq = (t & 7) << 2;
            float4 s = make_float4(0.f, 0.f, 0.f, 0.f);
            for (int p = 0; p < np; ++p) {
                float4 v = *(const float4*)&T_part[(((size_t)p * B_ + b) * 128 + ib + r) * 128 + c0 + kq];
                s.x += v.x; s.y += v.y; s.z += v.z; s.w += v.w;
            }
            *(float4*)&Ts[r][kq] = s;
        }
#pragma unroll
        for (int it = 0; it < 2; ++it) {
            int idx = it * 256 + t;
            int r = idx >> 3, kq = (idx & 7) << 2;
            *(float4*)&Wa[r][kq] = *(const float4*)&wA[(jb + r) * 128 + c0 + kq];
        }
        __syncthreads();
#pragma unroll
        for (int k = 0; k < 32; k += 4) {
            float4 wv[4], tv[2];
#pragma unroll
            for (int jj = 0; jj < 4; ++jj) wv[jj] = *(const float4*)&Wa[jj * 16 + ty][k];
#pragma unroll
            for (int ii = 0; ii < 2; ++ii) tv[ii] = *(const float4*)&Ts[ii * 16 + tx][k];
#pragma unroll
            for (int jj = 0; jj < 4; ++jj)
#pragma unroll
                for (int ii = 0; ii < 2; ++ii) {
                    acc[jj][ii] = fmaf(wv[jj].x, tv[ii].x, acc[jj][ii]);
                    acc[jj][ii] = fmaf(wv[jj].y, tv[ii].y, acc[jj][ii]);
                    acc[jj][ii] = fmaf(wv[jj].z, tv[ii].z, acc[jj][ii]);
                    acc[jj][ii] = fmaf(wv[jj].w, tv[ii].w, acc[jj][ii]);
                }
        }
    }
    const float* ZB = Zcat + b * 256;
    const float* ZV = ZB + 128;
#pragma unroll
    for (int jj = 0; jj < 4; ++jj) {
        int j = jb + jj * 16 + ty;
        float bj = bA[j];
#pragma unroll
        for (int ii = 0; ii < 2; ++ii) {
            int i = ib + ii * 16 + tx;
            float g = (acc[jj][ii] / ZB[i] + bj) / (4096.f * ZV[i]);
            float h = bf_hi(g);  float r1 = g - h;
            float m = bf_hi(r1);
            size_t o = ((size_t)b * 128 + j) * 128 + i;
            Gth[o] = (unsigned short)(__float_as_uint(h) >> 16);
            Gtm[o] = (unsigned short)(__float_as_uint(m) >> 16);
        }
    }
}

// ---------------------------------------------------------------------------
// k4: out[b,j,n] = sum_i expVT[n][i] * Gt(j,i)  (MFMA, 2-term G split).
__global__ __launch_bounds__(256, 4) void k4_out(
    const unsigned short* __restrict__ expVT,
    const unsigned short* __restrict__ Gth, const unsigned short* __restrict__ Gtm,
    float* __restrict__ out)
{
    __shared__ unsigned short Vs[128 * 136];   // [n][i] pitch 136

    const int t = threadIdx.x;
    const int lane = t & 63, w = t >> 6;
    const int col16 = lane & 15, quad = lane >> 4;
    const int b = blockIdx.y, nb = blockIdx.x * 128;

#pragma unroll
    for (int it = 0; it < 8; ++it) {
        int idx = it * 256 + t;
        int n = idx >> 4, o = idx & 15;
        int o2 = (o + 4 * (n & 3)) & 15;
        *(uint4*)&Vs[n * 136 + o2 * 8] =
            *(const uint4*)&expVT[((size_t)b * HW_ + nb + n) * 128 + o2 * 8];
    }
    __syncthreads();

    f32x4 acc[8][2];
#pragma unroll
    for (int i = 0; i < 8; ++i)
#pragma unroll
        for (int j = 0; j < 2; ++j) acc[i][j] = (f32x4){0.f,0.f,0.f,0.f};

    const unsigned short* gh = Gth + (size_t)b * 128 * 128;
    const unsigned short* gm = Gtm + (size_t)b * 128 * 128;

#pragma unroll
    for (int ks = 0; ks < 4; ++ks) {
        int ko = ks * 32 + quad * 8;
        bf16x8 vfr[2];
#pragma unroll
        for (int nt = 0; nt < 2; ++nt) {
            int n = w * 32 + nt * 16 + col16;
            vfr[nt] = *(const bf16x8*)&Vs[n * 136 + ko];
        }
#pragma unroll
        for (int mt = 0; mt < 8; ++mt) {
            int j = mt * 16 + col16;
            bf16x8 ah = *(const bf16x8*)&gh[j * 128 + ko];
            bf16x8 am = *(const bf16x8*)&gm[j * 128 + ko];
#pragma unroll
            for (int nt = 0; nt < 2; ++nt) {
                acc[mt][nt] = __builtin_amdgcn_mfma_f32_16x16x32_bf16(ah, vfr[nt], acc[mt][nt], 0, 0, 0);
                acc[mt][nt] = __builtin_amdgcn_mfma_f32_16x16x32_bf16(am, vfr[nt], acc[mt][nt], 0, 0, 0);
            }
        }
    }
    float* ob = out + (size_t)b * C_ * HW_;
#pragma unroll
    for (int mt = 0; mt < 8; ++mt)
#pragma unroll
        for (int nt = 0; nt < 2; ++nt)
#pragma unroll
            for (int r = 0; r < 4; ++r) {
                int j = mt * 16 + quad * 4 + r;
                int n = nb + w * 32 + nt * 16 + col16;
                ob[(size_t)j * HW_ + n] = acc[mt][nt][r];
            }
}

// ---------------------------------------------------------------------------
extern "C" void kernel_launch(void* const* d_in, const int* in_sizes, int n_in,
                              void* d_out, int out_size, void* d_ws, size_t ws_size,
                              hipStream_t stream)
{
    const float* x  = (const float*)d_in[0];
    const float* wA = (const float*)d_in[1];
    const float* bA = (const float*)d_in[2];
    const float* wB = (const float*)d_in[3];
    const float* bB = (const float*)d_in[4];
    const float* wV = (const float*)d_in[5];
    const float* bV = (const float*)d_in[6];
    float* out = (float*)d_out;

    // workspace (~98 MiB at np=16):
    //   Zcat 32K | Wh 64K | Wl 64K | expB 32M | expVT 32M | T_part np*2M | G 2M
    char* ws = (char*)d_ws;
    float*          Zcat  = (float*)ws;                       // 32768
    unsigned short* Wh    = (unsigned short*)(ws + 32768);    // 65536
    unsigned short* Wl    = (unsigned short*)(ws + 98304);    // 65536
    unsigned short* expB  = (unsigned short*)(ws + 163840);   // 33554432
    unsigned short* expVT = (unsigned short*)(ws + 33718272); // 33554432
    float*          T_part= (float*)(ws + 67272704);          // np*2097152

    int np = 16;
    while (np > 1 && 67272704ull + (size_t)np * 2097152 + 2097152 > ws_size) np >>= 1;

    unsigned short* Gth = (unsigned short*)(ws + 67272704 + (size_t)np * 2097152);
    unsigned short* Gtm = Gth + 128 * 128 * 32;

    hipMemsetAsync(Zcat, 0, 32768, stream);   // Zcat only

    k0_prep <<<dim3(32),     256, 0, stream>>>(wB, wV, Wh, Wl);
    k1_fused<<<dim3(16, 32), 512, 0, stream>>>(x, Wh, Wl, bB, bV, expB, expVT, Zcat);
    k2_T    <<<dim3(np, 32), 512, 0, stream>>>(x, expB, T_part, np);
    k3b_G   <<<dim3(8, 32),  256, 0, stream>>>(T_part, wA, bA, Zcat, Gth, Gtm, np);
    k4_out  <<<dim3(32, 32), 256, 0, stream>>>(expVT, Gth, Gtm, out);
}

// Round 6
// 233.086 us; speedup vs baseline: 1.2516x; 1.0853x over previous
//
#include <hip/hip_runtime.h>
#include <hip/hip_bf16.h>

// B=32, C=128, HW=4096.
//   E = [wB;wV]@x + bias ; expB/expV = exp(E) (bf16) ; ZB/ZV row sums
//   T[i,c] = sum_n expB[i,n]*x[c,n]
//   G[i,j] = ((T[i,:].wA[j,:])/ZB_i + bA[j]) / (4096*ZV_i)
//   out[j,n] = sum_i expV[i,n]*G[i,j]
// R6: k2 re-fused into k1 at 16-wave granularity. R5 evidence: k1 62us but
//   k2+k4+k3b ~ 190us, all latency-bound; k2's only reason to exist was tacc
//   VGPR pressure at 4/8-wave tiling. 1024-thr / 16-wave blocks shrink
//   per-wave state (eacc 8, tacc 16, 4+4-elem staging, est ~95 regs) under
//   the (1024,1) cap of 128. x staged in BOTH layouts via two coalesced load
//   patterns (no LDS scatter); expB never goes to HBM; T_part per n-chunk
//   (np=16, no atomics). Tripwire: FETCH>60MB per k1 dispatch = spill, revert.

#define B_  32
#define C_  128
#define HW_ 4096

typedef __attribute__((ext_vector_type(8))) __bf16 bf16x8;
typedef __attribute__((ext_vector_type(4))) float f32x4;

__device__ __forceinline__ unsigned int bf_rne(float f) {   // bf16 bits (RNE)
    unsigned int u = __float_as_uint(f);
    return (u + 0x7fffu + ((u >> 16) & 1u)) >> 16;
}
__device__ __forceinline__ float bf_hi(float f) {           // RNE-to-bf16, as fp32
    unsigned int u = __float_as_uint(f);
    return __uint_as_float((u + 0x7fffu + ((u >> 16) & 1u)) & 0xffff0000u);
}

// ---------------------------------------------------------------------------
// k0: split Wcat=[wB;wV] (256x128 fp32) into bf16 hi/lo arrays. grid 32x256.
__global__ __launch_bounds__(256) void k0_prep(
    const float* __restrict__ wB, const float* __restrict__ wV,
    unsigned short* __restrict__ Wh, unsigned short* __restrict__ Wl)
{
    int g = blockIdx.x * 256 + threadIdx.x;      // 0..8191 float4s
    int row = g >> 5, c4 = (g & 31) << 2;
    const float* src = (row < 128) ? &wB[row * 128] : &wV[(row - 128) * 128];
    float4 v = *(const float4*)&src[c4];
    float vv[4] = {v.x, v.y, v.z, v.w};
    unsigned int h[4], l[4];
#pragma unroll
    for (int e = 0; e < 4; ++e) {
        float hf = bf_hi(vv[e]);
        h[e] = __float_as_uint(hf) >> 16;
        l[e] = bf_rne(vv[e] - hf);
    }
    *(uint2*)&Wh[row * 128 + c4] = make_uint2(h[0] | (h[1] << 16), h[2] | (h[3] << 16));
    *(uint2*)&Wl[row * 128 + c4] = make_uint2(l[0] | (l[1] << 16), l[2] | (l[3] << 16));
}

// ---------------------------------------------------------------------------
// k1_fused: E-GEMM + exp + Z + T-GEMM + expVT copy-out. grid (16, 32),
// 1024 thr = 16 waves, (1024,1) => 16 waves/CU, cap 128 VGPR.
// Per wave: E 16 rows x 32 n; T tile 64 i x 16 c.
__global__ __launch_bounds__(1024, 1) void k1_fused(
    const float* __restrict__ x,
    const unsigned short* __restrict__ Wh, const unsigned short* __restrict__ Wl,
    const float* __restrict__ bB, const float* __restrict__ bV,
    unsigned short* __restrict__ expVT, float* __restrict__ T_part,
    float* __restrict__ Zcat)
{
    __shared__ unsigned short XT_h[32 * 136];   // [n][c] pitch 136 (E B-operand)
    __shared__ unsigned short XT_l[32 * 136];
    __shared__ unsigned short XN_h[128 * 40];   // [c][n] pitch 40 (T B-operand)
    __shared__ unsigned short XN_l[128 * 40];
    __shared__ unsigned short EBs[128 * 40];    // expB [i][n] pitch 40 (T A-operand)
    __shared__ unsigned short EVs[32 * 136];    // expV [n][i] pitch 136 (copy-out)
    __shared__ float bias_s[256];

    const int t = threadIdx.x;
    const int lane = t & 63, w = t >> 6;        // w = 0..15
    const int col16 = lane & 15, quad = lane >> 4;
    const int b = blockIdx.y;
    const int n0 = blockIdx.x * 256;
    const float* xb = x + (size_t)b * C_ * HW_;

    // staging pattern A (for XT): thread owns 4 c (cq0*4+cc) at one n (snA)
    const int snA = t & 31, cq0 = t >> 5;       // cq0 = 0..31
    // staging pattern B (for XN): thread owns 1 c row (scB), 4 n (sqB..+3)
    const int scB = t >> 3, sqB = (t & 7) * 4;

    const int rowbase = w * 16;                 // E rows for this wave (0..255)
    const int lbase = (w & 7) * 16;             // row base within 128-row projection
    const int boff = (w < 8) ? 0 : 128;
    const int mh = (w >> 3) * 64;               // T tile: i-half
    const int nh = (w & 7) * 16;                // T tile: c-sixteenth

    if (t < 256) bias_s[t] = (t < 128) ? bB[t] : bV[t - 128];

    f32x4 tacc[4];
    float zacc[4];
#pragma unroll
    for (int i = 0; i < 4; ++i) { tacc[i] = (f32x4){0.f,0.f,0.f,0.f}; zacc[i] = 0.f; }

    // prefetch subtile 0, both patterns
    float xrA[4], xrB[4];
#pragma unroll
    for (int cc = 0; cc < 4; ++cc)
        xrA[cc] = xb[(size_t)(cq0 * 4 + cc) * HW_ + n0 + snA];
    *(float4*)xrB = *(const float4*)&xb[(size_t)scB * HW_ + n0 + sqB];

    for (int st = 0; st < 8; ++st) {
        // convert pattern A (pre-barrier: overlaps wait)
        unsigned int ha[4], la[4];
#pragma unroll
        for (int e = 0; e < 4; ++e) {
            float hf = bf_hi(xrA[e]);
            ha[e] = __float_as_uint(hf) >> 16;
            la[e] = bf_rne(xrA[e] - hf);
        }
        __syncthreads();   // B1: previous subtile's T-GEMM reads / copy-out done
        *(uint2*)&XT_h[snA * 136 + cq0 * 4] = make_uint2(ha[0] | (ha[1] << 16), ha[2] | (ha[3] << 16));
        *(uint2*)&XT_l[snA * 136 + cq0 * 4] = make_uint2(la[0] | (la[1] << 16), la[2] | (la[3] << 16));
        {
            unsigned int hb[4], lb[4];
#pragma unroll
            for (int e = 0; e < 4; ++e) {
                float hf = bf_hi(xrB[e]);
                hb[e] = __float_as_uint(hf) >> 16;
                lb[e] = bf_rne(xrB[e] - hf);
            }
            *(uint2*)&XN_h[scB * 40 + sqB] = make_uint2(hb[0] | (hb[1] << 16), hb[2] | (hb[3] << 16));
            *(uint2*)&XN_l[scB * 40 + sqB] = make_uint2(lb[0] | (lb[1] << 16), lb[2] | (lb[3] << 16));
        }
        __syncthreads();   // B2: XT/XN visible
        // prefetch next subtile (overlaps E/T compute)
        if (st < 7) {
            int ns2 = n0 + (st + 1) * 32;
#pragma unroll
            for (int cc = 0; cc < 4; ++cc)
                xrA[cc] = xb[(size_t)(cq0 * 4 + cc) * HW_ + ns2 + snA];
            *(float4*)xrB = *(const float4*)&xb[(size_t)scB * HW_ + ns2 + sqB];
        }

        // --- E-GEMM: wave computes rows rowbase..+15 x 32 n, K=128 (c), 3 terms
        f32x4 e0 = (f32x4){0.f,0.f,0.f,0.f}, e1 = (f32x4){0.f,0.f,0.f,0.f};
#pragma unroll
        for (int ks = 0; ks < 4; ++ks) {
            int kc = ks * 32 + quad * 8;
            bf16x8 xh0 = *(const bf16x8*)&XT_h[col16 * 136 + kc];
            bf16x8 xl0 = *(const bf16x8*)&XT_l[col16 * 136 + kc];
            bf16x8 xh1 = *(const bf16x8*)&XT_h[(16 + col16) * 136 + kc];
            bf16x8 xl1 = *(const bf16x8*)&XT_l[(16 + col16) * 136 + kc];
            int row = rowbase + col16;
            bf16x8 wh = *(const bf16x8*)&Wh[row * 128 + kc];
            bf16x8 wl = *(const bf16x8*)&Wl[row * 128 + kc];
            e0 = __builtin_amdgcn_mfma_f32_16x16x32_bf16(wh, xh0, e0, 0, 0, 0);
            e0 = __builtin_amdgcn_mfma_f32_16x16x32_bf16(wh, xl0, e0, 0, 0, 0);
            e0 = __builtin_amdgcn_mfma_f32_16x16x32_bf16(wl, xh0, e0, 0, 0, 0);
            e1 = __builtin_amdgcn_mfma_f32_16x16x32_bf16(wh, xh1, e1, 0, 0, 0);
            e1 = __builtin_amdgcn_mfma_f32_16x16x32_bf16(wh, xl1, e1, 0, 0, 0);
            e1 = __builtin_amdgcn_mfma_f32_16x16x32_bf16(wl, xh1, e1, 0, 0, 0);
        }

        // --- epilogue: exp, Z accumulate, expB->EBs [i][n] / expV->EVs [n][i]
#pragma unroll
        for (int r = 0; r < 4; ++r) {
            int lrow = lbase + quad * 4 + r;     // 0..127 within projection
            float bb = bias_s[boff + lrow];
            float v0 = __expf(e0[r] + bb);
            float v1 = __expf(e1[r] + bb);
            zacc[r] += v0 + v1;
            if (w < 8) {
                EBs[lrow * 40 + col16]      = (unsigned short)bf_rne(v0);
                EBs[lrow * 40 + 16 + col16] = (unsigned short)bf_rne(v1);
            } else {
                EVs[col16 * 136 + lrow]        = (unsigned short)bf_rne(v0);
                EVs[(16 + col16) * 136 + lrow] = (unsigned short)bf_rne(v1);
            }
        }
        __syncthreads();   // B3: EBs/EVs ready (XN still valid from B2)

        // --- T-GEMM: K=32 (this subtile), wave tile 64 i x 16 c
        {
            int c = nh + col16;
            bf16x8 bh = *(const bf16x8*)&XN_h[c * 40 + quad * 8];
            bf16x8 bl = *(const bf16x8*)&XN_l[c * 40 + quad * 8];
#pragma unroll
            for (int mt = 0; mt < 4; ++mt) {
                bf16x8 a = *(const bf16x8*)&EBs[(mh + mt * 16 + col16) * 40 + quad * 8];
                tacc[mt] = __builtin_amdgcn_mfma_f32_16x16x32_bf16(a, bh, tacc[mt], 0, 0, 0);
                tacc[mt] = __builtin_amdgcn_mfma_f32_16x16x32_bf16(a, bl, tacc[mt], 0, 0, 0);
            }
        }
        // --- expVT copy-out (32 n x 128 i), one uint2 (4 bf16) per thread
        {
            int nl = t >> 5, io = (t & 31) * 4;
            *(uint2*)&expVT[((size_t)b * HW_ + n0 + st * 32 + nl) * 128 + io] =
                *(const uint2*)&EVs[nl * 136 + io];
        }
    }

    // T_part store (no atomics): chunk = blockIdx.x
    float* Tp = T_part + (((size_t)blockIdx.x * B_) + b) * 128 * 128;
#pragma unroll
    for (int mt = 0; mt < 4; ++mt)
#pragma unroll
        for (int r = 0; r < 4; ++r)
            Tp[(mh + mt * 16 + quad * 4 + r) * 128 + nh + col16] = tacc[mt][r];

    // Z atomics (one per row, reduced across col16 lanes first)
#pragma unroll
    for (int r = 0; r < 4; ++r) {
        float rs = zacc[r];
        rs += __shfl_xor(rs, 1, 16);
        rs += __shfl_xor(rs, 2, 16);
        rs += __shfl_xor(rs, 4, 16);
        rs += __shfl_xor(rs, 8, 16);
        if (col16 == 0)
            atomicAdd(&Zcat[b * 256 + boff + lbase + quad * 4 + r], rs);
    }
}

// ---------------------------------------------------------------------------
// k3b: G transposed + 2-way bf16 split; sums T_part inline during staging.
// grid (8, 32), block 256, fp32 VALU. Tiles 64 j x 32 i.
__global__ __launch_bounds__(256) void k3b_G(
    const float* __restrict__ T_part, const float* __restrict__ wA,
    const float* __restrict__ bA, const float* __restrict__ Zcat,
    unsigned short* __restrict__ Gth, unsigned short* __restrict__ Gtm, int np)
{
    const int t = threadIdx.x;
    const int tx = t & 15, ty = t >> 4;
    const int b = blockIdx.y;
    const int jb = (blockIdx.x >> 2) * 64;
    const int ib = (blockIdx.x & 3) * 32;

    __shared__ float Ts[32][36];
    __shared__ float Wa[64][36];

    float acc[4][2];
#pragma unroll
    for (int i = 0; i < 4; ++i)
#pragma unroll
        for (int j = 0; j < 2; ++j) acc[i][j] = 0.f;

    for (int c0 = 0; c0 < 128; c0 += 32) {
        __syncthreads();
        {
            int r = t >> 3, kq = (t & 7) << 2;
            float4 s = make_float4(0.f, 0.f, 0.f, 0.f);
            for (int p = 0; p < np; ++p) {
                float4 v = *(const float4*)&T_part[(((size_t)p * B_ + b) * 128 + ib + r) * 128 + c0 + kq];
                s.x += v.x; s.y += v.y; s.z += v.z; s.w += v.w;
            }
            *(float4*)&Ts[r][kq] = s;
        }
#pragma unroll
        for (int it = 0; it < 2; ++it) {
            int idx = it * 256 + t;
            int r = idx >> 3, kq = (idx & 7) << 2;
            *(float4*)&Wa[r][kq] = *(const float4*)&wA[(jb + r) * 128 + c0 + kq];
        }
        __syncthreads();
#pragma unroll
        for (int k = 0; k < 32; k += 4) {
            float4 wv[4], tv[2];
#pragma unroll
            for (int jj = 0; jj < 4; ++jj) wv[jj] = *(const float4*)&Wa[jj * 16 + ty][k];
#pragma unroll
            for (int ii = 0; ii < 2; ++ii) tv[ii] = *(const float4*)&Ts[ii * 16 + tx][k];
#pragma unroll
            for (int jj = 0; jj < 4; ++jj)
#pragma unroll
                for (int ii = 0; ii < 2; ++ii) {
                    acc[jj][ii] = fmaf(wv[jj].x, tv[ii].x, acc[jj][ii]);
                    acc[jj][ii] = fmaf(wv[jj].y, tv[ii].y, acc[jj][ii]);
                    acc[jj][ii] = fmaf(wv[jj].z, tv[ii].z, acc[jj][ii]);
                    acc[jj][ii] = fmaf(wv[jj].w, tv[ii].w, acc[jj][ii]);
                }
        }
    }
    const float* ZB = Zcat + b * 256;
    const float* ZV = ZB + 128;
#pragma unroll
    for (int jj = 0; jj < 4; ++jj) {
        int j = jb + jj * 16 + ty;
        float bj = bA[j];
#pragma unroll
        for (int ii = 0; ii < 2; ++ii) {
            int i = ib + ii * 16 + tx;
            float g = (acc[jj][ii] / ZB[i] + bj) / (4096.f * ZV[i]);
            float h = bf_hi(g);  float r1 = g - h;
            float m = bf_hi(r1);
            size_t o = ((size_t)b * 128 + j) * 128 + i;
            Gth[o] = (unsigned short)(__float_as_uint(h) >> 16);
            Gtm[o] = (unsigned short)(__float_as_uint(m) >> 16);
        }
    }
}

// ---------------------------------------------------------------------------
// k4: out[b,j,n] = sum_i expVT[n][i] * Gt(j,i)  (MFMA, 2-term G split).
__global__ __launch_bounds__(256, 4) void k4_out(
    const unsigned short* __restrict__ expVT,
    const unsigned short* __restrict__ Gth, const unsigned short* __restrict__ Gtm,
    float* __restrict__ out)
{
    __shared__ unsigned short Vs[128 * 136];   // [n][i] pitch 136

    const int t = threadIdx.x;
    const int lane = t & 63, w = t >> 6;
    const int col16 = lane & 15, quad = lane >> 4;
    const int b = blockIdx.y, nb = blockIdx.x * 128;

#pragma unroll
    for (int it = 0; it < 8; ++it) {
        int idx = it * 256 + t;
        int n = idx >> 4, o = idx & 15;
        int o2 = (o + 4 * (n & 3)) & 15;
        *(uint4*)&Vs[n * 136 + o2 * 8] =
            *(const uint4*)&expVT[((size_t)b * HW_ + nb + n) * 128 + o2 * 8];
    }
    __syncthreads();

    f32x4 acc[8][2];
#pragma unroll
    for (int i = 0; i < 8; ++i)
#pragma unroll
        for (int j = 0; j < 2; ++j) acc[i][j] = (f32x4){0.f,0.f,0.f,0.f};

    const unsigned short* gh = Gth + (size_t)b * 128 * 128;
    const unsigned short* gm = Gtm + (size_t)b * 128 * 128;

#pragma unroll
    for (int ks = 0; ks < 4; ++ks) {
        int ko = ks * 32 + quad * 8;
        bf16x8 vfr[2];
#pragma unroll
        for (int nt = 0; nt < 2; ++nt) {
            int n = w * 32 + nt * 16 + col16;
            vfr[nt] = *(const bf16x8*)&Vs[n * 136 + ko];
        }
#pragma unroll
        for (int mt = 0; mt < 8; ++mt) {
            int j = mt * 16 + col16;
            bf16x8 ah = *(const bf16x8*)&gh[j * 128 + ko];
            bf16x8 am = *(const bf16x8*)&gm[j * 128 + ko];
#pragma unroll
            for (int nt = 0; nt < 2; ++nt) {
                acc[mt][nt] = __builtin_amdgcn_mfma_f32_16x16x32_bf16(ah, vfr[nt], acc[mt][nt], 0, 0, 0);
                acc[mt][nt] = __builtin_amdgcn_mfma_f32_16x16x32_bf16(am, vfr[nt], acc[mt][nt], 0, 0, 0);
            }
        }
    }
    float* ob = out + (size_t)b * C_ * HW_;
#pragma unroll
    for (int mt = 0; mt < 8; ++mt)
#pragma unroll
        for (int nt = 0; nt < 2; ++nt)
#pragma unroll
            for (int r = 0; r < 4; ++r) {
                int j = mt * 16 + quad * 4 + r;
                int n = nb + w * 32 + nt * 16 + col16;
                ob[(size_t)j * HW_ + n] = acc[mt][nt][r];
            }
}

// ---------------------------------------------------------------------------
extern "C" void kernel_launch(void* const* d_in, const int* in_sizes, int n_in,
                              void* d_out, int out_size, void* d_ws, size_t ws_size,
                              hipStream_t stream)
{
    const float* x  = (const float*)d_in[0];
    const float* wA = (const float*)d_in[1];
    const float* bA = (const float*)d_in[2];
    const float* wB = (const float*)d_in[3];
    const float* bB = (const float*)d_in[4];
    const float* wV = (const float*)d_in[5];
    const float* bV = (const float*)d_in[6];
    float* out = (float*)d_out;

    // workspace (~69 MiB):
    //   Zcat 32K | Wh 64K | Wl 64K | expVT 32M | T_part 16*2M | G 2M
    char* ws = (char*)d_ws;
    float*          Zcat  = (float*)ws;                       // 32768
    unsigned short* Wh    = (unsigned short*)(ws + 32768);    // 65536
    unsigned short* Wl    = (unsigned short*)(ws + 98304);    // 65536
    unsigned short* expVT = (unsigned short*)(ws + 163840);   // 33554432
    float*          T_part= (float*)(ws + 33718272);          // 16*2097152
    unsigned short* Gth   = (unsigned short*)(ws + 33718272 + 16 * 2097152);
    unsigned short* Gtm   = Gth + 128 * 128 * 32;

    hipMemsetAsync(Zcat, 0, 32768, stream);   // Zcat only

    k0_prep <<<dim3(32),     256,  0, stream>>>(wB, wV, Wh, Wl);
    k1_fused<<<dim3(16, 32), 1024, 0, stream>>>(x, Wh, Wl, bB, bV, expVT, T_part, Zcat);
    k3b_G   <<<dim3(8, 32),  256,  0, stream>>>(T_part, wA, bA, Zcat, Gth, Gtm, 16);
    k4_out  <<<dim3(32, 32), 256,  0, stream>>>(expVT, Gth, Gtm, out);
}